// Round 1
// baseline (346.893 us; speedup 1.0000x reference)
//
#include <hip/hip_runtime.h>
#include <stdint.h>

typedef __attribute__((ext_vector_type(8))) short bf16x8;
typedef __attribute__((ext_vector_type(4))) float f32x4;

__device__ __forceinline__ unsigned short f32_to_bf16(float f) {
  union { float f; unsigned int u; } v; v.f = f;
  unsigned int u = v.u;
  u += 0x7fffu + ((u >> 16) & 1u);   // round-to-nearest-even
  return (unsigned short)(u >> 16);
}

__device__ __forceinline__ void gload_lds16(const unsigned short* g, unsigned short* lds_p) {
  __builtin_amdgcn_global_load_lds(
      (const __attribute__((address_space(1))) unsigned int*)g,
      (__attribute__((address_space(3))) unsigned int*)lds_p,
      16, 0, 0);
}

// ---------------------------------------------------------------------------
// C[M,N] = scale * A[M,K] x B[N,K]^T  (bf16 raw ushort, K-contiguous rows).
// 256x256 tile, BK=64, 512 threads = 8 waves (2Mx4N), per-wave 128x64 output.
// Counted-vmcnt software pipeline (T3+T4+T5):
//   - K-tile split into 2 K-half "slots" per matrix: [256 rows][32 k] regions,
//     64B row stride -> ds_read_b128 is bank-balanced (no swizzle needed),
//     and global_load_lds destinations stay linear.
//   - slot ring: 2 buffers x {A,B} x {kk0,kk1} = 8 regions, 128 KiB LDS.
//   - 4 phases per K-tile: (kk, m-half); 16 MFMA/phase; B-frags reused
//     across m-halves (4-or-8 ds_read_b128 per phase).
//   - each phase issues one half-slot prefetch 6 phases ahead of its use;
//     vmcnt(8) twice per tile (never 0 in the main loop); raw s_barrier +
//     explicit lgkmcnt(0) (no __syncthreads drain). Tail drains 8->4->0.
// Liveness proof (slot s=4t+i; i: 0=A.kk0 1=B.kk0 2=A.kk1 3=B.kk1):
//   reads: slots 4t+{0,1} in phases 4t+{0,1}; 4t+{2,3} in phases 4t+{2,3}.
//   issue at phase Q targets slot Q+6; its region tenant (slot Q-2) was last
//   read in phase <= Q-1, separated by a barrier preceded by lgkmcnt(0).
//   vmcnt(8) at phase 4t+1 (issued through slot 4t+7) lands slots <= 4t+3;
//   at 4t+3 (issued through 4t+9) lands slots <= 4t+5. NT >= 2 required.
// ---------------------------------------------------------------------------

#define VM8  asm volatile("s_waitcnt vmcnt(8)" ::: "memory")
#define VM4  asm volatile("s_waitcnt vmcnt(4)" ::: "memory")
#define VM0_ asm volatile("s_waitcnt vmcnt(0)" ::: "memory")
#define VMNO ((void)0)

#define ISSUE_A(KT, KK) do {                                                  \
    const unsigned short* ga_ = As0 + (KT) * 64 + (KK) * 32;                  \
    unsigned short* la_ = &lds[(((KT) & 1) << 15) + (KK) * 8192 + t * 8];     \
    gload_lds16(ga_, la_);                                                    \
    gload_lds16(ga_ + a128, la_ + 4096);                                      \
  } while (0)

#define ISSUE_B(KT, KK) do {                                                  \
    const unsigned short* gb_ = Bs0 + (KT) * 64 + (KK) * 32;                  \
    unsigned short* lb_ = &lds[(((KT) & 1) << 15) + 16384 + (KK) * 8192 + t * 8]; \
    gload_lds16(gb_, lb_);                                                    \
    gload_lds16(gb_ + b128, lb_ + 4096);                                      \
  } while (0)

#define PH(BUFB, KK, MH, LOADB, ISSUE_CODE, VMC) do {                         \
    const int ab_ = (BUFB) + (KK) * 8192;                                     \
    if (LOADB) {                                                              \
      const int bb2_ = (BUFB) + 16384 + (KK) * 8192;                          \
      _Pragma("unroll")                                                       \
      for (int ni_ = 0; ni_ < 4; ++ni_)                                       \
        bfr[ni_] = *(const bf16x8*)&lds[bb2_ + (wc + ni_ * 16 + lrow) * 32 + q8e]; \
    }                                                                         \
    bf16x8 af_[4];                                                            \
    _Pragma("unroll")                                                         \
    for (int mi_ = 0; mi_ < 4; ++mi_)                                         \
      af_[mi_] = *(const bf16x8*)&lds[ab_ + (wr + (MH) * 64 + mi_ * 16 + lrow) * 32 + q8e]; \
    ISSUE_CODE;                                                               \
    __builtin_amdgcn_s_setprio(1);                                            \
    _Pragma("unroll")                                                         \
    for (int mi_ = 0; mi_ < 4; ++mi_) {                                       \
      _Pragma("unroll")                                                       \
      for (int ni_ = 0; ni_ < 4; ++ni_)                                       \
        acc[(MH) * 4 + mi_][ni_] = __builtin_amdgcn_mfma_f32_16x16x32_bf16(   \
            af_[mi_], bfr[ni_], acc[(MH) * 4 + mi_][ni_], 0, 0, 0);           \
    }                                                                         \
    __builtin_amdgcn_s_setprio(0);                                            \
    VMC;                                                                      \
    asm volatile("s_waitcnt lgkmcnt(0)" ::: "memory");                        \
    __builtin_amdgcn_s_barrier();                                             \
    asm volatile("" ::: "memory");                                            \
  } while (0)

template<int MODE>
__global__ __launch_bounds__(512, 2)
void gemm_bt(const unsigned short* __restrict__ A,
             const unsigned short* __restrict__ Bm,
             void* __restrict__ Cv,
             int M, int N, int K, int lda, int ldb, int ldc,
             long sA_, long sB_, long sC_,
             float scale)
{
  __shared__ unsigned short lds[65536];   // 128 KiB: 2 buf x {A,B} x {kk0,kk1} x [256][32]

  const int bz = blockIdx.z;
  const unsigned short* Ab = A + (long)bz * sA_;
  const unsigned short* Bb = Bm + (long)bz * sB_;

  const int m0 = blockIdx.x * 256;
  const int n0 = blockIdx.y * 256;

  const int t = threadIdx.x;       // 0..511
  const int lane = t & 63;
  const int w = t >> 6;            // 0..7 -> 2x4 grid of 128x64 subtiles
  const int wr = (w >> 2) * 128;
  const int wc = (w & 3) * 64;
  const int lrow = lane & 15;
  const int q8e = (lane >> 4) * 8;

  // staging: half-slot = 256 rows x 32 k = 1024 x 16B chunks; thread t covers
  // chunks t and t+512. chunk ci -> row ci>>2, k-chunk ci&3.
  const int row0 = t >> 2;
  const int kc0 = (t & 3) * 8;
  const unsigned short* As0 = Ab + (long)(m0 + row0) * lda + kc0;
  const unsigned short* Bs0 = Bb + (long)(n0 + row0) * ldb + kc0;
  const long a128 = (long)lda * 128;   // +128 rows (chunk ci+512)
  const long b128 = (long)ldb * 128;

  f32x4 acc[8][4];
#pragma unroll
  for (int i = 0; i < 8; ++i)
#pragma unroll
    for (int j = 0; j < 4; ++j)
      acc[i][j] = (f32x4){0.f, 0.f, 0.f, 0.f};

  const int NT = K >> 6;   // K-tiles of 64; NT >= 2 required

  // prologue: slots 0..5 (tile0 all, tile1 kk0), then land slots 0,1.
  ISSUE_A(0, 0); ISSUE_B(0, 0);
  ISSUE_A(0, 1); ISSUE_B(0, 1);
  ISSUE_A(1, 0); ISSUE_B(1, 0);
  VM8;
  __builtin_amdgcn_s_barrier();
  asm volatile("" ::: "memory");

  bf16x8 bfr[4];
  int kt = 0;
  for (; kt < NT - 2; ++kt) {
    const int bb = (kt & 1) << 15;
    PH(bb, 0, 0, 1, ISSUE_A(kt + 1, 1), VMNO);
    PH(bb, 0, 1, 0, ISSUE_B(kt + 1, 1), VM8);
    PH(bb, 1, 0, 1, ISSUE_A(kt + 2, 0), VMNO);
    PH(bb, 1, 1, 0, ISSUE_B(kt + 2, 0), VM8);
  }
  { // kt = NT-2: last prefetches (tile NT-1 kk1), start drain
    const int bb = (kt & 1) << 15;
    PH(bb, 0, 0, 1, ISSUE_A(kt + 1, 1), VMNO);
    PH(bb, 0, 1, 0, ISSUE_B(kt + 1, 1), VM8);
    PH(bb, 1, 0, 1, VMNO, VMNO);
    PH(bb, 1, 1, 0, VMNO, VM4);
    ++kt;
  }
  { // kt = NT-1: no prefetch; finish drain
    const int bb = (kt & 1) << 15;
    PH(bb, 0, 0, 1, VMNO, VMNO);
    PH(bb, 0, 1, 0, VMNO, VM0_);
    PH(bb, 1, 0, 1, VMNO, VMNO);
    PH(bb, 1, 1, 0, VMNO, VMNO);
  }

  // epilogue: C/D layout col = lane&15, row = (lane>>4)*4 + reg
  const int cl = lane & 15;
  const int rq = (lane >> 4) * 4;

  if (MODE == 2) {
    float* Cb = (float*)Cv + (long)bz * sC_;
#pragma unroll
    for (int mig = 0; mig < 8; ++mig) {
      const int rowb = m0 + wr + (mig >> 2) * 64 + (mig & 3) * 16 + rq;
#pragma unroll
      for (int ni = 0; ni < 4; ++ni) {
        const int col = n0 + wc + ni * 16 + cl;
#pragma unroll
        for (int r = 0; r < 4; ++r)
          Cb[(long)(rowb + r) * ldc + col] = acc[mig][ni][r] * scale;
      }
    }
  } else {
    unsigned short* Cb = (unsigned short*)Cv + (long)bz * sC_;
#pragma unroll
    for (int mig = 0; mig < 8; ++mig) {
      const int rowb = m0 + wr + (mig >> 2) * 64 + (mig & 3) * 16 + rq;
#pragma unroll
      for (int ni = 0; ni < 4; ++ni) {
        const int col = n0 + wc + ni * 16 + cl;
#pragma unroll
        for (int r = 0; r < 4; ++r)
          Cb[(long)(rowb + r) * ldc + col] = f32_to_bf16(acc[mig][ni][r]);
      }
    }
  }
}

// softmax over rows of 2048 fp32 -> bf16
__global__ __launch_bounds__(256)
void softmax_rows(const float* __restrict__ dist, unsigned short* __restrict__ attn) {
  const long row = blockIdx.x;
  const float4* in = (const float4*)(dist + row * 2048);
  const int t = threadIdx.x;
  float4 v0 = in[t];
  float4 v1 = in[t + 256];

  float m = fmaxf(fmaxf(fmaxf(v0.x, v0.y), fmaxf(v0.z, v0.w)),
                  fmaxf(fmaxf(v1.x, v1.y), fmaxf(v1.z, v1.w)));
#pragma unroll
  for (int off = 32; off > 0; off >>= 1)
    m = fmaxf(m, __shfl_xor(m, off, 64));

  __shared__ float redm[4];
  __shared__ float reds[4];
  if ((t & 63) == 0) redm[t >> 6] = m;
  __syncthreads();
  m = fmaxf(fmaxf(redm[0], redm[1]), fmaxf(redm[2], redm[3]));

  float e[8];
  e[0] = __expf(v0.x - m); e[1] = __expf(v0.y - m);
  e[2] = __expf(v0.z - m); e[3] = __expf(v0.w - m);
  e[4] = __expf(v1.x - m); e[5] = __expf(v1.y - m);
  e[6] = __expf(v1.z - m); e[7] = __expf(v1.w - m);

  float s = ((e[0] + e[1]) + (e[2] + e[3])) + ((e[4] + e[5]) + (e[6] + e[7]));
#pragma unroll
  for (int off = 32; off > 0; off >>= 1)
    s += __shfl_xor(s, off, 64);
  if ((t & 63) == 0) reds[t >> 6] = s;
  __syncthreads();
  s = (reds[0] + reds[1]) + (reds[2] + reds[3]);

  const float inv = 1.0f / s;
  ushort4 o0, o1;
  o0.x = f32_to_bf16(e[0] * inv); o0.y = f32_to_bf16(e[1] * inv);
  o0.z = f32_to_bf16(e[2] * inv); o0.w = f32_to_bf16(e[3] * inv);
  o1.x = f32_to_bf16(e[4] * inv); o1.y = f32_to_bf16(e[5] * inv);
  o1.z = f32_to_bf16(e[6] * inv); o1.w = f32_to_bf16(e[7] * inv);
  *(ushort4*)(attn + row * 2048 + t * 4) = o0;
  *(ushort4*)(attn + row * 2048 + 1024 + t * 4) = o1;
}

// Fused cast of Wq,Wk,Wv,Wo (1M elems each) + x (8M elems) into one contiguous
// bf16 destination region. Segment boundaries are block-aligned.
__global__ __launch_bounds__(256)
void cast_all(const float* __restrict__ Wq, const float* __restrict__ Wk,
              const float* __restrict__ Wv, const float* __restrict__ Wo,
              const float* __restrict__ x, unsigned short* __restrict__ dst) {
  const long i = ((long)blockIdx.x * 256 + threadIdx.x) * 4;
  const float* src;
  long off;
  if (i < 4194304) {
    const int which = (int)(i >> 20);
    src = (which == 0) ? Wq : (which == 1) ? Wk : (which == 2) ? Wv : Wo;
    off = i & 1048575;
  } else {
    src = x;
    off = i - 4194304;
  }
  float4 v = *(const float4*)(src + off);
  ushort4 o;
  o.x = f32_to_bf16(v.x); o.y = f32_to_bf16(v.y);
  o.z = f32_to_bf16(v.z); o.w = f32_to_bf16(v.w);
  *(ushort4*)(dst + i) = o;
}

extern "C" void kernel_launch(void* const* d_in, const int* in_sizes, int n_in,
                              void* d_out, int out_size, void* d_ws, size_t ws_size,
                              hipStream_t stream) {
  const float* x  = (const float*)d_in[0];
  const float* Wq = (const float*)d_in[1];
  const float* Wk = (const float*)d_in[2];
  const float* Wv = (const float*)d_in[3];
  const float* Wo = (const float*)d_in[4];

  const long Bn = 4, S = 2048, D = 1024;
  const long MS = Bn * S;               // 8192

  float* out_p  = (float*)d_out;        // [B,S,D] = 8192x1024 fp32
  float* weight = out_p + MS * D;       // [B,S,S] = 4x2048x2048 fp32

  // workspace layout (ushort elements), 72 MB total:
  unsigned short* Wqb = (unsigned short*)d_ws;   // [2048,1024]: Wq rows then Wk rows
  unsigned short* Wvb = Wqb + 2 * D * D;
  unsigned short* Wob = Wvb + D * D;
  unsigned short* xb  = Wob + D * D;    // [8192,1024]
  unsigned short* qk  = xb + MS * D;    // [8192,2048]: cols 0..1023 = q, 1024.. = k
  unsigned short* vtb = qk + MS * 2048; // [4][1024][2048]  (v transposed per batch)
  unsigned short* attn = qk;            // alias (qk dead after dist): [4][2048][2048]
  unsigned short* ctx  = xb;            // alias (xb dead after v GEMM): [8192,1024]

  // one fused cast: weights + x -> contiguous bf16 region at Wqb
  cast_all<<<12288, 256, 0, stream>>>(Wq, Wk, Wv, Wo, x, Wqb);

  // qk = x [Wq;Wk]^T  (8192 x 2048 x 1024)
  gemm_bt<0><<<dim3(32, 8, 1), 512, 0, stream>>>(xb, Wqb, qk, 8192, 2048, 1024,
                                                 1024, 1024, 2048, 0, 0, 0, 1.f);
  // vT[b] = Wv x[b]^T : M=1024, N=2048, K=1024 -> vtb [b][1024][2048]
  gemm_bt<0><<<dim3(4, 8, 4), 512, 0, stream>>>(Wvb, xb, vtb, 1024, 2048, 1024,
                                                1024, 1024, 2048, 0, S * D, D * S, 1.f);
  // dist[b] = scale * q[b] k[b]^T -> fp32 straight into d_out weight region
  gemm_bt<2><<<dim3(8, 8, 4), 512, 0, stream>>>(qk, qk + 1024, weight, 2048, 2048, 1024,
                                                2048, 2048, 2048,
                                                S * 2048, S * 2048, S * S,
                                                0.04419417382415922f);
  // attn = softmax(dist) -> bf16 (aliases qk)
  softmax_rows<<<(int)(Bn * S), 256, 0, stream>>>(weight, attn);
  // ctx[b] = attn[b] vT[b]^T : M=2048, N=1024, K=2048
  gemm_bt<0><<<dim3(8, 4, 4), 512, 0, stream>>>(attn, vtb, ctx, 2048, 1024, 2048,
                                                2048, 2048, 1024,
                                                S * S, D * S, S * D, 1.f);
  // out = ctx Wo^T -> fp32 d_out
  gemm_bt<2><<<dim3(32, 4, 1), 512, 0, stream>>>(ctx, Wob, out_p, 8192, 1024, 1024,
                                                 1024, 1024, 1024, 0, 0, 0, 1.f);
}

// Round 2
// 308.121 us; speedup vs baseline: 1.1258x; 1.1258x over previous
//
#include <hip/hip_runtime.h>
#include <stdint.h>

typedef __attribute__((ext_vector_type(8))) short bf16x8;
typedef __attribute__((ext_vector_type(4))) float f32x4;

__device__ __forceinline__ unsigned short f32_to_bf16(float f) {
  union { float f; unsigned int u; } v; v.f = f;
  unsigned int u = v.u;
  u += 0x7fffu + ((u >> 16) & 1u);   // round-to-nearest-even
  return (unsigned short)(u >> 16);
}

__device__ __forceinline__ void gload_lds16(const unsigned short* g, unsigned short* lds_p) {
  __builtin_amdgcn_global_load_lds(
      (const __attribute__((address_space(1))) unsigned int*)g,
      (__attribute__((address_space(3))) unsigned int*)lds_p,
      16, 0, 0);
}

// ---------------------------------------------------------------------------
// Shared scheme for both GEMM variants:
//   C[M,N] = scale * A[M,K] x B[N,K]^T (bf16 ushort, K-contiguous rows).
//   LDS half-slot = [rows][32 k] with 64B row stride.
//   T2 swizzle (both-sides, rule 21): logical chunk (row,k8) lives at physical
//   k8' = k8 ^ ((row>>1)&3).  Staging keeps LDS dest LINEAR (global_load_lds
//   requirement) and pre-swizzles the GLOBAL k-offset:
//     kc0 = ((t&3) ^ ((t>>3)&3)) * 8        (row = t>>2; +512-chunk row+128
//     leaves (row>>1)&3 unchanged, so same kc works for both gloads).
//   Read side: k8p = (lane>>4) ^ ((lrow>>1)&3)  — per-thread CONSTANT
//   ((row>>1)&3 == (lrow>>1)&3 since all row bases are multiples of 16).
//   Per 16-lane LDS quarter this puts exactly 2 lanes per bank (the b128
//   floor); unswizzled it was 8/bank -> the 3.1M conflicts seen in round 1.
// ---------------------------------------------------------------------------

#define VM8  asm volatile("s_waitcnt vmcnt(8)" ::: "memory")
#define VM6  asm volatile("s_waitcnt vmcnt(6)" ::: "memory")
#define VM4  asm volatile("s_waitcnt vmcnt(4)" ::: "memory")
#define VM3  asm volatile("s_waitcnt vmcnt(3)" ::: "memory")
#define VM0_ asm volatile("s_waitcnt vmcnt(0)" ::: "memory")
#define VMNO ((void)0)

// ============================ 256x256, 4-phase =============================
// 512 thr = 8 waves (2Mx4N), per-wave 128x64. 128 KiB LDS ring:
// 2 buf x {A,B} x {kk0,kk1} x [256][32]. vmcnt(8) twice per tile.

#define ISSUE_A(KT, KK) do {                                                  \
    const unsigned short* ga_ = As0 + (KT) * 64 + (KK) * 32;                  \
    unsigned short* la_ = &lds[(((KT) & 1) << 15) + (KK) * 8192 + t * 8];     \
    gload_lds16(ga_, la_);                                                    \
    gload_lds16(ga_ + a128, la_ + 4096);                                      \
  } while (0)

#define ISSUE_B(KT, KK) do {                                                  \
    const unsigned short* gb_ = Bs0 + (KT) * 64 + (KK) * 32;                  \
    unsigned short* lb_ = &lds[(((KT) & 1) << 15) + 16384 + (KK) * 8192 + t * 8]; \
    gload_lds16(gb_, lb_);                                                    \
    gload_lds16(gb_ + b128, lb_ + 4096);                                      \
  } while (0)

#define PH(BUFB, KK, MH, LOADB, ISSUE_CODE, VMC) do {                         \
    const int ab_ = (BUFB) + (KK) * 8192;                                     \
    if (LOADB) {                                                              \
      const int bb2_ = (BUFB) + 16384 + (KK) * 8192;                          \
      _Pragma("unroll")                                                       \
      for (int ni_ = 0; ni_ < 4; ++ni_)                                       \
        bfr[ni_] = *(const bf16x8*)&lds[bb2_ + (wc + ni_ * 16 + lrow) * 32 + q8s]; \
    }                                                                         \
    bf16x8 af_[4];                                                            \
    _Pragma("unroll")                                                         \
    for (int mi_ = 0; mi_ < 4; ++mi_)                                         \
      af_[mi_] = *(const bf16x8*)&lds[ab_ + (wr + (MH) * 64 + mi_ * 16 + lrow) * 32 + q8s]; \
    ISSUE_CODE;                                                               \
    __builtin_amdgcn_s_setprio(1);                                            \
    _Pragma("unroll")                                                         \
    for (int mi_ = 0; mi_ < 4; ++mi_) {                                       \
      _Pragma("unroll")                                                       \
      for (int ni_ = 0; ni_ < 4; ++ni_)                                       \
        acc[(MH) * 4 + mi_][ni_] = __builtin_amdgcn_mfma_f32_16x16x32_bf16(   \
            af_[mi_], bfr[ni_], acc[(MH) * 4 + mi_][ni_], 0, 0, 0);           \
    }                                                                         \
    __builtin_amdgcn_s_setprio(0);                                            \
    VMC;                                                                      \
    asm volatile("s_waitcnt lgkmcnt(0)" ::: "memory");                        \
    __builtin_amdgcn_s_barrier();                                             \
    asm volatile("" ::: "memory");                                            \
  } while (0)

template<int MODE>
__global__ __launch_bounds__(512, 2)
void gemm_bt(const unsigned short* __restrict__ A,
             const unsigned short* __restrict__ Bm,
             void* __restrict__ Cv,
             int M, int N, int K, int lda, int ldb, int ldc,
             long sA_, long sB_, long sC_,
             float scale)
{
  __shared__ unsigned short lds[65536];   // 128 KiB

  const int bz = blockIdx.z;
  const unsigned short* Ab = A + (long)bz * sA_;
  const unsigned short* Bb = Bm + (long)bz * sB_;

  const int m0 = blockIdx.x * 256;
  const int n0 = blockIdx.y * 256;

  const int t = threadIdx.x;       // 0..511
  const int lane = t & 63;
  const int w = t >> 6;            // 0..7 -> 2x4 grid of 128x64 subtiles
  const int wr = (w >> 2) * 128;
  const int wc = (w & 3) * 64;
  const int lrow = lane & 15;
  const int q8s = (((lane >> 4) ^ ((lrow >> 1) & 3)) * 8);  // swizzled k-chunk

  // staging: thread t covers chunks t and t+512; pre-swizzled global k-offset
  const int row0 = t >> 2;
  const int kc0 = (((t & 3) ^ ((t >> 3) & 3)) * 8);
  const unsigned short* As0 = Ab + (long)(m0 + row0) * lda + kc0;
  const unsigned short* Bs0 = Bb + (long)(n0 + row0) * ldb + kc0;
  const long a128 = (long)lda * 128;
  const long b128 = (long)ldb * 128;

  f32x4 acc[8][4];
#pragma unroll
  for (int i = 0; i < 8; ++i)
#pragma unroll
    for (int j = 0; j < 4; ++j)
      acc[i][j] = (f32x4){0.f, 0.f, 0.f, 0.f};

  const int NT = K >> 6;   // NT >= 2

  ISSUE_A(0, 0); ISSUE_B(0, 0);
  ISSUE_A(0, 1); ISSUE_B(0, 1);
  ISSUE_A(1, 0); ISSUE_B(1, 0);
  VM8;
  __builtin_amdgcn_s_barrier();
  asm volatile("" ::: "memory");

  bf16x8 bfr[4];
  int kt = 0;
  for (; kt < NT - 2; ++kt) {
    const int bb = (kt & 1) << 15;
    PH(bb, 0, 0, 1, ISSUE_A(kt + 1, 1), VMNO);
    PH(bb, 0, 1, 0, ISSUE_B(kt + 1, 1), VM8);
    PH(bb, 1, 0, 1, ISSUE_A(kt + 2, 0), VMNO);
    PH(bb, 1, 1, 0, ISSUE_B(kt + 2, 0), VM8);
  }
  { // kt = NT-2
    const int bb = (kt & 1) << 15;
    PH(bb, 0, 0, 1, ISSUE_A(kt + 1, 1), VMNO);
    PH(bb, 0, 1, 0, ISSUE_B(kt + 1, 1), VM8);
    PH(bb, 1, 0, 1, VMNO, VMNO);
    PH(bb, 1, 1, 0, VMNO, VM4);
    ++kt;
  }
  { // kt = NT-1
    const int bb = (kt & 1) << 15;
    PH(bb, 0, 0, 1, VMNO, VMNO);
    PH(bb, 0, 1, 0, VMNO, VM0_);
    PH(bb, 1, 0, 1, VMNO, VMNO);
    PH(bb, 1, 1, 0, VMNO, VMNO);
  }

  const int cl = lane & 15;
  const int rq = (lane >> 4) * 4;

  if (MODE == 2) {
    float* Cb = (float*)Cv + (long)bz * sC_;
#pragma unroll
    for (int mig = 0; mig < 8; ++mig) {
      const int rowb = m0 + wr + (mig >> 2) * 64 + (mig & 3) * 16 + rq;
#pragma unroll
      for (int ni = 0; ni < 4; ++ni) {
        const int col = n0 + wc + ni * 16 + cl;
#pragma unroll
        for (int r = 0; r < 4; ++r)
          Cb[(long)(rowb + r) * ldc + col] = acc[mig][ni][r] * scale;
      }
    }
  } else {
    unsigned short* Cb = (unsigned short*)Cv + (long)bz * sC_;
#pragma unroll
    for (int mig = 0; mig < 8; ++mig) {
      const int rowb = m0 + wr + (mig >> 2) * 64 + (mig & 3) * 16 + rq;
#pragma unroll
      for (int ni = 0; ni < 4; ++ni) {
        const int col = n0 + wc + ni * 16 + cl;
#pragma unroll
        for (int r = 0; r < 4; ++r)
          Cb[(long)(rowb + r) * ldc + col] = f32_to_bf16(acc[mig][ni][r]);
      }
    }
  }
}

// ============================ 128x256, 2-phase =============================
// For shapes where a 256x256 grid underfills (M or N = 1024 -> 128 blocks).
// 512 thr = 8 waves (2Mx4N), per-wave 64x64, acc[4][4]. 96 KiB LDS ring:
// 2 buf x {A[128][32]x2kk, B[256][32]x2kk}. Per tile 6 gloads (A:1, B:2 per
// kk). Steady state: P0 issues trio(kt+1,kk1), P1 issues trio(kt+2,kk0);
// both end with vmcnt(6). Tail: 6 -> 3 -> 0.

#define ISSUE_A1(KT, KK) do {                                                 \
    gload_lds16(As0 + (KT) * 64 + (KK) * 32,                                  \
                &lds[((KT) & 1) * 24576 + (KK) * 4096 + t * 8]);              \
  } while (0)

#define ISSUE_B1(KT, KK) do {                                                 \
    const unsigned short* gb_ = Bs0 + (KT) * 64 + (KK) * 32;                  \
    unsigned short* lb_ = &lds[((KT) & 1) * 24576 + 8192 + (KK) * 8192 + t * 8]; \
    gload_lds16(gb_, lb_);                                                    \
    gload_lds16(gb_ + b128, lb_ + 4096);                                      \
  } while (0)

#define PH2(BUFB, KK, ISSUE_CODE, VMC) do {                                   \
    const int ab_ = (BUFB) + (KK) * 4096;                                     \
    const int bb_ = (BUFB) + 8192 + (KK) * 8192;                              \
    bf16x8 af_[4], bf_[4];                                                    \
    _Pragma("unroll")                                                         \
    for (int i_ = 0; i_ < 4; ++i_) {                                          \
      af_[i_] = *(const bf16x8*)&lds[ab_ + (wr + i_ * 16 + lrow) * 32 + q8s]; \
      bf_[i_] = *(const bf16x8*)&lds[bb_ + (wc + i_ * 16 + lrow) * 32 + q8s]; \
    }                                                                         \
    ISSUE_CODE;                                                               \
    __builtin_amdgcn_s_setprio(1);                                            \
    _Pragma("unroll")                                                         \
    for (int mi_ = 0; mi_ < 4; ++mi_) {                                       \
      _Pragma("unroll")                                                       \
      for (int ni_ = 0; ni_ < 4; ++ni_)                                       \
        acc[mi_][ni_] = __builtin_amdgcn_mfma_f32_16x16x32_bf16(              \
            af_[mi_], bf_[ni_], acc[mi_][ni_], 0, 0, 0);                      \
    }                                                                         \
    __builtin_amdgcn_s_setprio(0);                                            \
    VMC;                                                                      \
    asm volatile("s_waitcnt lgkmcnt(0)" ::: "memory");                        \
    __builtin_amdgcn_s_barrier();                                             \
    asm volatile("" ::: "memory");                                            \
  } while (0)

template<int MODE>
__global__ __launch_bounds__(512, 2)
void gemm_bt_128(const unsigned short* __restrict__ A,
                 const unsigned short* __restrict__ Bm,
                 void* __restrict__ Cv,
                 int M, int N, int K, int lda, int ldb, int ldc,
                 long sA_, long sB_, long sC_,
                 float scale)
{
  __shared__ unsigned short lds[49152];   // 96 KiB

  const int bz = blockIdx.z;
  const unsigned short* Ab = A + (long)bz * sA_;
  const unsigned short* Bb = Bm + (long)bz * sB_;

  const int m0 = blockIdx.x * 128;
  const int n0 = blockIdx.y * 256;

  const int t = threadIdx.x;       // 0..511
  const int lane = t & 63;
  const int w = t >> 6;            // 0..7 -> 2x4 grid of 64x64 subtiles
  const int wr = (w >> 2) * 64;
  const int wc = (w & 3) * 64;
  const int lrow = lane & 15;
  const int q8s = (((lane >> 4) ^ ((lrow >> 1) & 3)) * 8);

  const int row0 = t >> 2;         // A: row 0..127; B: rows row0, row0+128
  const int kc0 = (((t & 3) ^ ((t >> 3) & 3)) * 8);
  const unsigned short* As0 = Ab + (long)(m0 + row0) * lda + kc0;
  const unsigned short* Bs0 = Bb + (long)(n0 + row0) * ldb + kc0;
  const long b128 = (long)ldb * 128;

  f32x4 acc[4][4];
#pragma unroll
  for (int i = 0; i < 4; ++i)
#pragma unroll
    for (int j = 0; j < 4; ++j)
      acc[i][j] = (f32x4){0.f, 0.f, 0.f, 0.f};

  const int NT = K >> 6;   // NT >= 2

  ISSUE_A1(0, 0); ISSUE_B1(0, 0);
  ISSUE_A1(0, 1); ISSUE_B1(0, 1);
  ISSUE_A1(1, 0); ISSUE_B1(1, 0);
  VM6;
  __builtin_amdgcn_s_barrier();
  asm volatile("" ::: "memory");

  int kt = 0;
  for (; kt < NT - 2; ++kt) {
    const int bb = (kt & 1) * 24576;
    PH2(bb, 0, { ISSUE_A1(kt + 1, 1); ISSUE_B1(kt + 1, 1); }, VM6);
    PH2(bb, 1, { ISSUE_A1(kt + 2, 0); ISSUE_B1(kt + 2, 0); }, VM6);
  }
  { // kt = NT-2
    const int bb = (kt & 1) * 24576;
    PH2(bb, 0, { ISSUE_A1(kt + 1, 1); ISSUE_B1(kt + 1, 1); }, VM6);
    PH2(bb, 1, {}, VM3);
    ++kt;
  }
  { // kt = NT-1
    const int bb = (kt & 1) * 24576;
    PH2(bb, 0, {}, VM0_);
    PH2(bb, 1, {}, VMNO);
  }

  const int cl = lane & 15;
  const int rq = (lane >> 4) * 4;

  if (MODE == 2) {
    float* Cb = (float*)Cv + (long)bz * sC_;
#pragma unroll
    for (int mi = 0; mi < 4; ++mi) {
      const int rowb = m0 + wr + mi * 16 + rq;
#pragma unroll
      for (int ni = 0; ni < 4; ++ni) {
        const int col = n0 + wc + ni * 16 + cl;
#pragma unroll
        for (int r = 0; r < 4; ++r)
          Cb[(long)(rowb + r) * ldc + col] = acc[mi][ni][r] * scale;
      }
    }
  } else {
    unsigned short* Cb = (unsigned short*)Cv + (long)bz * sC_;
#pragma unroll
    for (int mi = 0; mi < 4; ++mi) {
      const int rowb = m0 + wr + mi * 16 + rq;
#pragma unroll
      for (int ni = 0; ni < 4; ++ni) {
        const int col = n0 + wc + ni * 16 + cl;
#pragma unroll
        for (int r = 0; r < 4; ++r)
          Cb[(long)(rowb + r) * ldc + col] = f32_to_bf16(acc[mi][ni][r]);
      }
    }
  }
}

// softmax over rows of 2048 fp32 -> bf16
__global__ __launch_bounds__(256)
void softmax_rows(const float* __restrict__ dist, unsigned short* __restrict__ attn) {
  const long row = blockIdx.x;
  const float4* in = (const float4*)(dist + row * 2048);
  const int t = threadIdx.x;
  float4 v0 = in[t];
  float4 v1 = in[t + 256];

  float m = fmaxf(fmaxf(fmaxf(v0.x, v0.y), fmaxf(v0.z, v0.w)),
                  fmaxf(fmaxf(v1.x, v1.y), fmaxf(v1.z, v1.w)));
#pragma unroll
  for (int off = 32; off > 0; off >>= 1)
    m = fmaxf(m, __shfl_xor(m, off, 64));

  __shared__ float redm[4];
  __shared__ float reds[4];
  if ((t & 63) == 0) redm[t >> 6] = m;
  __syncthreads();
  m = fmaxf(fmaxf(redm[0], redm[1]), fmaxf(redm[2], redm[3]));

  float e[8];
  e[0] = __expf(v0.x - m); e[1] = __expf(v0.y - m);
  e[2] = __expf(v0.z - m); e[3] = __expf(v0.w - m);
  e[4] = __expf(v1.x - m); e[5] = __expf(v1.y - m);
  e[6] = __expf(v1.z - m); e[7] = __expf(v1.w - m);

  float s = ((e[0] + e[1]) + (e[2] + e[3])) + ((e[4] + e[5]) + (e[6] + e[7]));
#pragma unroll
  for (int off = 32; off > 0; off >>= 1)
    s += __shfl_xor(s, off, 64);
  if ((t & 63) == 0) reds[t >> 6] = s;
  __syncthreads();
  s = (reds[0] + reds[1]) + (reds[2] + reds[3]);

  const float inv = 1.0f / s;
  ushort4 o0, o1;
  o0.x = f32_to_bf16(e[0] * inv); o0.y = f32_to_bf16(e[1] * inv);
  o0.z = f32_to_bf16(e[2] * inv); o0.w = f32_to_bf16(e[3] * inv);
  o1.x = f32_to_bf16(e[4] * inv); o1.y = f32_to_bf16(e[5] * inv);
  o1.z = f32_to_bf16(e[6] * inv); o1.w = f32_to_bf16(e[7] * inv);
  *(ushort4*)(attn + row * 2048 + t * 4) = o0;
  *(ushort4*)(attn + row * 2048 + 1024 + t * 4) = o1;
}

// Fused cast of Wq,Wk,Wv,Wo (1M elems each) + x (8M elems) -> contiguous bf16.
__global__ __launch_bounds__(256)
void cast_all(const float* __restrict__ Wq, const float* __restrict__ Wk,
              const float* __restrict__ Wv, const float* __restrict__ Wo,
              const float* __restrict__ x, unsigned short* __restrict__ dst) {
  const long i = ((long)blockIdx.x * 256 + threadIdx.x) * 4;
  const float* src;
  long off;
  if (i < 4194304) {
    const int which = (int)(i >> 20);
    src = (which == 0) ? Wq : (which == 1) ? Wk : (which == 2) ? Wv : Wo;
    off = i & 1048575;
  } else {
    src = x;
    off = i - 4194304;
  }
  float4 v = *(const float4*)(src + off);
  ushort4 o;
  o.x = f32_to_bf16(v.x); o.y = f32_to_bf16(v.y);
  o.z = f32_to_bf16(v.z); o.w = f32_to_bf16(v.w);
  *(ushort4*)(dst + i) = o;
}

extern "C" void kernel_launch(void* const* d_in, const int* in_sizes, int n_in,
                              void* d_out, int out_size, void* d_ws, size_t ws_size,
                              hipStream_t stream) {
  const float* x  = (const float*)d_in[0];
  const float* Wq = (const float*)d_in[1];
  const float* Wk = (const float*)d_in[2];
  const float* Wv = (const float*)d_in[3];
  const float* Wo = (const float*)d_in[4];

  const long Bn = 4, S = 2048, D = 1024;
  const long MS = Bn * S;               // 8192

  float* out_p  = (float*)d_out;        // [B,S,D] = 8192x1024 fp32
  float* weight = out_p + MS * D;       // [B,S,S] = 4x2048x2048 fp32

  // workspace layout (ushort elements):
  unsigned short* Wqb = (unsigned short*)d_ws;   // [2048,1024]: Wq rows then Wk rows
  unsigned short* Wvb = Wqb + 2 * D * D;
  unsigned short* Wob = Wvb + D * D;
  unsigned short* xb  = Wob + D * D;    // [8192,1024]
  unsigned short* qk  = xb + MS * D;    // [8192,2048]: cols 0..1023 = q, 1024.. = k
  unsigned short* vtb = qk + MS * 2048; // [4][1024][2048]  (v transposed per batch)
  unsigned short* attn = qk;            // alias (qk dead after dist)
  unsigned short* ctx  = xb;            // alias (xb dead after v GEMM)

  cast_all<<<12288, 256, 0, stream>>>(Wq, Wk, Wv, Wo, x, Wqb);

  // qk = x [Wq;Wk]^T  (8192 x 2048 x 1024)             grid 256
  gemm_bt<0><<<dim3(32, 8, 1), 512, 0, stream>>>(xb, Wqb, qk, 8192, 2048, 1024,
                                                 1024, 1024, 2048, 0, 0, 0, 1.f);
  // vT[b] = Wv x[b]^T : M=1024, N=2048, K=1024         grid 256
  gemm_bt_128<0><<<dim3(8, 8, 4), 512, 0, stream>>>(Wvb, xb, vtb, 1024, 2048, 1024,
                                                    1024, 1024, 2048, 0, S * D, D * S, 1.f);
  // dist[b] = scale * q[b] k[b]^T -> fp32              grid 256
  gemm_bt<2><<<dim3(8, 8, 4), 512, 0, stream>>>(qk, qk + 1024, weight, 2048, 2048, 1024,
                                                2048, 2048, 2048,
                                                S * 2048, S * 2048, S * S,
                                                0.04419417382415922f);
  // attn = softmax(dist) -> bf16
  softmax_rows<<<(int)(Bn * S), 256, 0, stream>>>(weight, attn);
  // ctx[b] = attn[b] vT[b]^T : M=2048, N=1024, K=2048  grid 256
  gemm_bt_128<0><<<dim3(16, 4, 4), 512, 0, stream>>>(attn, vtb, ctx, 2048, 1024, 2048,
                                                     2048, 2048, 1024,
                                                     S * S, D * S, S * D, 1.f);
  // out = ctx Wo^T -> fp32                             grid 256
  gemm_bt_128<2><<<dim3(64, 4, 1), 512, 0, stream>>>(ctx, Wob, out_p, 8192, 1024, 1024,
                                                     1024, 1024, 1024, 0, 0, 0, 1.f);
}